// Round 13
// baseline (1475.840 us; speedup 1.0000x reference)
//
#include <hip/hip_runtime.h>
#include <hip/hip_bf16.h>

#define B_ 128
#define S_ 512
#define C_ 512
#define H_ 512
#define NC_ 64
#define T_ 25
#define TEXTW (T_ + 1)

typedef __attribute__((ext_vector_type(8))) short bf16x8;
typedef __attribute__((ext_vector_type(8))) unsigned short u16x8;
typedef __attribute__((ext_vector_type(4))) float f32x4;

__device__ __forceinline__ float bf2f(unsigned short u) {
    union { unsigned int i; float f; } v; v.i = ((unsigned int)u) << 16; return v.f;
}
__device__ __forceinline__ unsigned short f2bf(float f) {
    union { float f; unsigned int u; } v; v.f = f;
    unsigned int r = (v.u + 0x7FFFu + ((v.u >> 16) & 1u)) >> 16;
    return (unsigned short)r;
}
__device__ __forceinline__ void gload_lds16(const void* g, void* l) {
    __builtin_amdgcn_global_load_lds(
        (const __attribute__((address_space(1))) unsigned int*)g,
        (__attribute__((address_space(3))) unsigned int*)l, 16, 0, 0);
}
__device__ __forceinline__ float fast_tanh(float x) {
    float e = __builtin_amdgcn_exp2f(2.885390082f * x);
    return 1.f - 2.f * __builtin_amdgcn_rcpf(e + 1.f);
}
__device__ __forceinline__ float fast_sigmoid(float x) {
    return __builtin_amdgcn_rcpf(1.f + __builtin_amdgcn_exp2f(-1.442695041f * x));
}

// ---------------- setup: init state + all weight conversions ----------------
__global__ __launch_bounds__(512) void setup_k(
    const float* __restrict__ Wi, const float* __restrict__ Wh,
    const float* __restrict__ Wl, const float* __restrict__ Ul,
    unsigned short* __restrict__ Wt_bf, unsigned short* __restrict__ Wh_bf,
    unsigned short* __restrict__ WU_t,
    float* __restrict__ c2, unsigned short* __restrict__ inp) {
    int blk = blockIdx.x, tid = threadIdx.x;
    if (blk < 128) {
        c2[blk * 512 + tid] = 0.f;
        c2[65536 + blk * 512 + tid] = 0.f;
        inp[blk * 1024 + 512 + tid] = 0;
    } else if (blk < 640) {
        int n = blk - 128;
        Wt_bf[n * 512 + tid] = f2bf(Wi[tid * 512 + n]);
    } else if (blk < 1152) {
        int i = (blk - 640) * 512 + tid;
        Wh_bf[i] = f2bf(Wh[i]);
    } else {
        int np = blk - 1152;
        int h = np >> 2, g = np & 3;
        {
            float v = Wl[(size_t)tid * 2048 + g * 512 + h];
            WU_t[(size_t)np * 1024 + tid] = f2bf(v);
        }
        {
            float v = Ul[(size_t)tid * 2048 + g * 512 + h];
            WU_t[(size_t)np * 1024 + 512 + tid] = f2bf(v);
        }
    }
}

// ---------------- x f32 -> bf16 ----------------
__global__ __launch_bounds__(256) void conv_x(const float* __restrict__ in,
                                              unsigned short* __restrict__ out) {
    int i = blockIdx.x * 256 + threadIdx.x;
    const float4 v = ((const float4*)in)[i];
    ushort4 o;
    o.x = f2bf(v.x); o.y = f2bf(v.y); o.z = f2bf(v.z); o.w = f2bf(v.w);
    ((ushort4*)out)[i] = o;
}

// ---------------- proj = x @ W_i2h via MFMA (bf16) ----------------
__global__ __launch_bounds__(256) void gemm_proj(const unsigned short* __restrict__ A,
                                                 const unsigned short* __restrict__ Bt,
                                                 unsigned short* __restrict__ Cm) {
    __shared__ unsigned short As[128 * 64];
    __shared__ unsigned short Bs[128 * 64];
    int tid = threadIdx.x;
    int lane = tid & 63;
    int wid = tid >> 6;
    int wr = wid >> 1, wc = wid & 1;
    int row0 = blockIdx.y * 128;
    int col0 = blockIdx.x * 128;

    f32x4 acc[4][4];
#pragma unroll
    for (int i = 0; i < 4; ++i)
#pragma unroll
        for (int j = 0; j < 4; ++j) acc[i][j] = (f32x4){0.f, 0.f, 0.f, 0.f};

    for (int k0 = 0; k0 < 512; k0 += 64) {
#pragma unroll
        for (int i = 0; i < 4; ++i) {
            int e = tid + i * 256;
            int r = e >> 3, cc = e & 7;
            int cs = cc ^ (r & 7);
            gload_lds16(A + (size_t)(row0 + r) * 512 + k0 + cs * 8, &As[e * 8]);
        }
#pragma unroll
        for (int i = 0; i < 4; ++i) {
            int e = tid + i * 256;
            int r = e >> 3, cc = e & 7;
            int cs = cc ^ (r & 7);
            gload_lds16(Bt + (size_t)(col0 + r) * 512 + k0 + cs * 8, &Bs[e * 8]);
        }
        __syncthreads();
#pragma unroll
        for (int ks = 0; ks < 2; ++ks) {
            bf16x8 a[4], b[4];
#pragma unroll
            for (int i = 0; i < 4; ++i) {
                int m = wr * 64 + i * 16 + (lane & 15);
                int ch = (ks * 4 + (lane >> 4)) ^ (m & 7);
                a[i] = *(const bf16x8*)&As[(m * 8 + ch) * 8];
            }
#pragma unroll
            for (int j = 0; j < 4; ++j) {
                int n = wc * 64 + j * 16 + (lane & 15);
                int ch = (ks * 4 + (lane >> 4)) ^ (n & 7);
                b[j] = *(const bf16x8*)&Bs[(n * 8 + ch) * 8];
            }
#pragma unroll
            for (int i = 0; i < 4; ++i)
#pragma unroll
                for (int j = 0; j < 4; ++j)
                    acc[i][j] = __builtin_amdgcn_mfma_f32_16x16x32_bf16(a[i], b[j], acc[i][j], 0, 0, 0);
        }
        __syncthreads();
    }
#pragma unroll
    for (int i = 0; i < 4; ++i)
#pragma unroll
        for (int j = 0; j < 4; ++j) {
            int gcol = col0 + wc * 64 + j * 16 + (lane & 15);
#pragma unroll
            for (int r = 0; r < 4; ++r) {
                int grow = row0 + wr * 64 + i * 16 + (lane >> 4) * 4 + r;
                Cm[(size_t)grow * 512 + gcol] = f2bf(acc[i][j][r]);
            }
        }
}

// ---------------- z = [ctx|h] @ WU_t^T; 32 blocks x 512 thr; BK=128 ----------------
__global__ __launch_bounds__(512) void z_gemm(
    const unsigned short* __restrict__ inp, const unsigned short* __restrict__ Bt,
    const float* __restrict__ pc, const float* __restrict__ pm,
    const float* __restrict__ ps, float* __restrict__ Z) {
    __shared__ unsigned short As[128 * 128];   // 32 KB
    __shared__ unsigned short Bs[64 * 128];    // 16 KB
    int tid = threadIdx.x;
    int lane = tid & 63;
    int wave = tid >> 6;
    int wr = wave >> 2, wc = wave & 3;
    int col0 = blockIdx.x * 64;

    float cw0[4], cw1[4];
    int rr[4], csv[4];
#pragma unroll
    for (int i = 0; i < 4; ++i) {
        int e = tid + i * 512;
        int r = e >> 4, cc = e & 15;
        rr[i] = r; csv[i] = cc ^ (r & 15);
        float m0 = pm[r], m1 = pm[128 + r];
        float s0 = ps[r], s1 = ps[128 + r];
        float M = fmaxf(m0, m1);
        float w0 = __builtin_amdgcn_exp2f(1.442695041f * (m0 - M));
        float w1 = __builtin_amdgcn_exp2f(1.442695041f * (m1 - M));
        float inv = 1.f / (w0 * s0 + w1 * s1);
        cw0[i] = w0 * inv; cw1[i] = w1 * inv;
    }

    f32x4 acc[4];
#pragma unroll
    for (int i = 0; i < 4; ++i) acc[i] = (f32x4){0.f, 0.f, 0.f, 0.f};

    for (int k0 = 0; k0 < 1024; k0 += 128) {
        if (k0 < 512) {
#pragma unroll
            for (int i = 0; i < 4; ++i) {
                int e = tid + i * 512;
                int kb = k0 + csv[i] * 8;
                const float* c0p = pc + rr[i] * 512 + kb;
                const float* c1p = pc + 65536 + rr[i] * 512 + kb;
                float4 c0a = *(const float4*)c0p;
                float4 c0b = *(const float4*)(c0p + 4);
                float4 c1a = *(const float4*)c1p;
                float4 c1b = *(const float4*)(c1p + 4);
                u16x8 o;
                o[0] = f2bf(cw0[i] * c0a.x + cw1[i] * c1a.x);
                o[1] = f2bf(cw0[i] * c0a.y + cw1[i] * c1a.y);
                o[2] = f2bf(cw0[i] * c0a.z + cw1[i] * c1a.z);
                o[3] = f2bf(cw0[i] * c0a.w + cw1[i] * c1a.w);
                o[4] = f2bf(cw0[i] * c0b.x + cw1[i] * c1b.x);
                o[5] = f2bf(cw0[i] * c0b.y + cw1[i] * c1b.y);
                o[6] = f2bf(cw0[i] * c0b.z + cw1[i] * c1b.z);
                o[7] = f2bf(cw0[i] * c0b.w + cw1[i] * c1b.w);
                *(u16x8*)&As[e * 8] = o;
            }
        } else {
#pragma unroll
            for (int i = 0; i < 4; ++i) {
                int e = tid + i * 512;
                gload_lds16(inp + (size_t)rr[i] * 1024 + k0 + csv[i] * 8, &As[e * 8]);
            }
        }
#pragma unroll
        for (int i = 0; i < 2; ++i) {
            int e = tid + i * 512;
            int r = e >> 4, cc = e & 15;
            int cs = cc ^ (r & 15);
            gload_lds16(Bt + (size_t)(col0 + r) * 1024 + k0 + cs * 8, &Bs[e * 8]);
        }
        __syncthreads();
#pragma unroll
        for (int ks = 0; ks < 4; ++ks) {
            bf16x8 a[4], bfr;
#pragma unroll
            for (int i = 0; i < 4; ++i) {
                int m = wr * 64 + i * 16 + (lane & 15);
                int ch = (ks * 4 + (lane >> 4)) ^ (m & 15);
                a[i] = *(const bf16x8*)&As[(m * 16 + ch) * 8];
            }
            {
                int n = wc * 16 + (lane & 15);
                int ch = (ks * 4 + (lane >> 4)) ^ (n & 15);
                bfr = *(const bf16x8*)&Bs[(n * 16 + ch) * 8];
            }
#pragma unroll
            for (int i = 0; i < 4; ++i)
                acc[i] = __builtin_amdgcn_mfma_f32_16x16x32_bf16(a[i], bfr, acc[i], 0, 0, 0);
        }
        __syncthreads();
    }
#pragma unroll
    for (int i = 0; i < 4; ++i) {
        int gcol = col0 + wc * 16 + (lane & 15);
#pragma unroll
        for (int r = 0; r < 4; ++r) {
            int grow = wr * 64 + i * 16 + (lane >> 4) * 4 + r;
            Z[(size_t)grow * 2048 + gcol] = acc[i][r];
        }
    }
}

// ---------------- fused: gates(t)+hp(t) [dup per half] + flash E/C(t+1) ----------------
// 256 blocks = (half, b); 1024 threads. t==-1: ectx only. t==24: gates only.
__global__ __launch_bounds__(1024) void ghp_e2(
    const float* __restrict__ z, const int* __restrict__ text,
    const float* __restrict__ Wl, const float* __restrict__ bl,
    const unsigned short* __restrict__ Whb, const float* __restrict__ bh2h,
    float* __restrict__ c2, float* __restrict__ hs_t,
    unsigned short* __restrict__ inp,
    const unsigned short* __restrict__ proj, const unsigned short* __restrict__ xb,
    const float* __restrict__ Wscore,
    float* __restrict__ pc, float* __restrict__ pm, float* __restrict__ ps, int t) {
    __shared__ float shg[512];
    __shared__ float wk[16][512];   // hp partials, then flash-ctx partials
    __shared__ float sh_hp[512];
    __shared__ float sh_red[32];    // m_w [0..16), s_w [16..32)
    int blk = blockIdx.x;
    int half = blk >> 7, b = blk & 127;
    int tid = threadIdx.x, wave = tid >> 6, lane = tid & 63;

    if (t >= 0) {
        // ---- gates (duplicated per half; each half owns its c copy) ----
        if (tid < 512) {
            int ch = text[b * TEXTW + t];
            const float* wrow = Wl + (size_t)(512 + ch) * 2048;
            float4 zv = *(const float4*)(z + (size_t)b * 2048 + tid * 4);
            float zi = zv.x + bl[tid] + wrow[tid];
            float zf = zv.y + bl[512 + tid] + wrow[512 + tid];
            float zg = zv.z + bl[1024 + tid] + wrow[1024 + tid];
            float zo = zv.w + bl[1536 + tid] + wrow[1536 + tid];
            float ig = fast_sigmoid(zi);
            float fg = fast_sigmoid(zf);
            float gg = fast_tanh(zg);
            float og = fast_sigmoid(zo);
            int idx = half * 65536 + b * 512 + tid;
            float cn = fg * c2[idx] + ig * gg;
            c2[idx] = cn;
            float hn = og * fast_tanh(cn);
            if (half == 0) {
                hs_t[b * 512 + tid] = hn;
                inp[b * 1024 + 512 + tid] = f2bf(hn);
            }
            shg[tid] = hn;
        }
        __syncthreads();
        if (t >= T_ - 1) return;
        // ---- hp (full GEMV, duplicated per half); wave owns 32 k, lane owns 8 cols ----
        {
            float r8[8] = {0.f, 0.f, 0.f, 0.f, 0.f, 0.f, 0.f, 0.f};
#pragma unroll 4
            for (int kk = 0; kk < 32; ++kk) {
                int k = wave * 32 + kk;
                float hv = shg[k];
                u16x8 wv = *(const u16x8*)(Whb + k * 512 + lane * 8);
#pragma unroll
                for (int jj = 0; jj < 8; ++jj) r8[jj] = fmaf(hv, bf2f(wv[jj]), r8[jj]);
            }
#pragma unroll
            for (int jj = 0; jj < 8; ++jj) wk[wave][lane * 8 + jj] = r8[jj];
        }
        __syncthreads();
        if (tid < 512) {
            float s = bh2h[tid];
#pragma unroll
            for (int w = 0; w < 16; ++w) s += wk[w][tid];
            sh_hp[tid] = s;
        }
        __syncthreads();
    } else {
        if (tid < 512) sh_hp[tid] = bh2h[tid];
        __syncthreads();
    }

    // ---- flash E+C: wave owns 16 s-rows; online softmax + ctx accumulation ----
    {
        float4 h0 = *(const float4*)(sh_hp + lane * 8);
        float4 h1 = *(const float4*)(sh_hp + lane * 8 + 4);
        float4 w0 = *(const float4*)(Wscore + lane * 8);
        float4 w1 = *(const float4*)(Wscore + lane * 8 + 4);
        float hp_r[8] = {h0.x, h0.y, h0.z, h0.w, h1.x, h1.y, h1.z, h1.w};
        float w_r[8]  = {w0.x, w0.y, w0.z, w0.w, w1.x, w1.y, w1.z, w1.w};
        float w2_r[8];
#pragma unroll
        for (int j = 0; j < 8; ++j) w2_r[j] = -2.f * w_r[j];
        int j0 = lane * 8;
        float m_run = -1e30f, s_run = 0.f;
        float ctx[8] = {0.f, 0.f, 0.f, 0.f, 0.f, 0.f, 0.f, 0.f};
        int s0g = half * 256 + wave * 16;
#pragma unroll 2
        for (int i = 0; i < 16; ++i) {
            size_t rowoff = ((size_t)(b * 512 + s0g + i) << 9);
            const bf16x8 pv = *(const bf16x8*)(proj + rowoff + j0);
            const u16x8 xv = *(const u16x8*)(xb + rowoff + j0);
            float a = 0.f;
#pragma unroll
            for (int j = 0; j < 8; ++j) {
                float xvv = bf2f((unsigned short)pv[j]) + hp_r[j];
                float r = __builtin_amdgcn_rcpf(__builtin_amdgcn_exp2f(2.885390082f * xvv) + 1.f);
                a += w_r[j];
                a = fmaf(w2_r[j], r, a);
            }
#pragma unroll
            for (int off = 32; off > 0; off >>= 1) a += __shfl_xor(a, off, 64);
            if (a > m_run) {   // wave-uniform branch
                float sc = __builtin_amdgcn_exp2f(1.442695041f * (m_run - a));
                s_run *= sc;
#pragma unroll
                for (int j = 0; j < 8; ++j) ctx[j] *= sc;
                m_run = a;
            }
            float p = __builtin_amdgcn_exp2f(1.442695041f * (a - m_run));
            s_run += p;
#pragma unroll
            for (int j = 0; j < 8; ++j) ctx[j] = fmaf(p, bf2f(xv[j]), ctx[j]);
        }
        if (lane == 0) { sh_red[wave] = m_run; sh_red[16 + wave] = s_run; }
#pragma unroll
        for (int j = 0; j < 8; ++j) wk[wave][j0 + j] = ctx[j];
    }
    __syncthreads();

    // ---- combine 16 wave-partials ----
    if (tid < 512) {
        float M = sh_red[0];
#pragma unroll
        for (int w = 1; w < 16; ++w) M = fmaxf(M, sh_red[w]);
        float ssum = 0.f, csum = 0.f;
#pragma unroll
        for (int w = 0; w < 16; ++w) {
            float sc = __builtin_amdgcn_exp2f(1.442695041f * (sh_red[w] - M));
            ssum = fmaf(sc, sh_red[16 + w], ssum);
            csum = fmaf(sc, wk[w][tid], csum);
        }
        pc[(size_t)(half * 128 + b) * 512 + tid] = csum;
        if (tid == 0) { pm[half * 128 + b] = M; ps[half * 128 + b] = ssum; }
    }
}

// ---------------- probs = hs @ W_gen + b_gen; 400 blocks x 64 thr, 8 rows/block ----------------
__global__ __launch_bounds__(64) void gen_probs(const float* __restrict__ hs,
                                                const float* __restrict__ Wg,
                                                const float* __restrict__ bg,
                                                float* __restrict__ out) {
    __shared__ float sh[8][512];
    int r0 = blockIdx.x * 8;
    int tid = threadIdx.x;
#pragma unroll
    for (int q = 0; q < 8; ++q) {
        int row = r0 + q;
        int b = row / T_, t = row % T_;
        const float* hrow = hs + ((size_t)t * B_ + b) * H_;
        for (int i = tid; i < 512; i += 64) sh[q][i] = hrow[i];
    }
    __syncthreads();
    float acc[8];
#pragma unroll
    for (int q = 0; q < 8; ++q) acc[q] = bg[tid];
#pragma unroll 4
    for (int k = 0; k < 512; ++k) {
        float w = Wg[k * 64 + tid];
#pragma unroll
        for (int q = 0; q < 8; ++q) acc[q] = fmaf(sh[q][k], w, acc[q]);
    }
#pragma unroll
    for (int q = 0; q < 8; ++q) out[(size_t)(r0 + q) * 64 + tid] = acc[q];
}

extern "C" void kernel_launch(void* const* d_in, const int* in_sizes, int n_in,
                              void* d_out, int out_size, void* d_ws, size_t ws_size,
                              hipStream_t stream) {
    const float* x       = (const float*)d_in[0];
    const int*   text    = (const int*)d_in[1];
    const float* W_i2h   = (const float*)d_in[2];
    const float* W_h2h   = (const float*)d_in[3];
    const float* b_h2h   = (const float*)d_in[4];
    const float* W_score = (const float*)d_in[5];
    const float* W_lstm  = (const float*)d_in[6];
    const float* U_lstm  = (const float*)d_in[7];
    const float* b_lstm  = (const float*)d_in[8];
    const float* W_gen   = (const float*)d_in[9];
    const float* b_gen   = (const float*)d_in[10];
    float* out = (float*)d_out;

    char* ws = (char*)d_ws;
    unsigned short* x_bf    = (unsigned short*)ws;                 // 67,108,864
    unsigned short* proj_bf = (unsigned short*)(ws + 67108864);    // 67,108,864
    unsigned short* Wt_bf   = (unsigned short*)(ws + 134217728);   //    524,288
    unsigned short* Wh_bf   = (unsigned short*)(ws + 134742016);   //    524,288
    unsigned short* WU_t    = (unsigned short*)(ws + 135266304);   //  4,194,304
    float* c2      = (float*)(ws + 139460608);                     //    524,288 (2 copies)
    unsigned short* inp_bf = (unsigned short*)(ws + 139984896);    //    262,144
    float* z_buf   = (float*)(ws + 140247040);                     //  1,048,576
    float* pc      = (float*)(ws + 141295616);                     //    524,288
    float* pm      = (float*)(ws + 141819904);                     //      1,024
    float* ps      = (float*)(ws + 141820928);                     //      1,024
    float* hs      = (float*)(ws + 141821952);                     // 13,107,200

    setup_k<<<dim3(3200), 512, 0, stream>>>(W_i2h, W_h2h, W_lstm, U_lstm,
                                            Wt_bf, Wh_bf, WU_t, c2, inp_bf);
    conv_x<<<dim3(32768), 256, 0, stream>>>(x, x_bf);
    gemm_proj<<<dim3(4, 512), 256, 0, stream>>>(x_bf, Wt_bf, proj_bf);
    // partial ectx for t=0 with hp = b_h2h
    ghp_e2<<<dim3(256), 1024, 0, stream>>>(z_buf, text, W_lstm, b_lstm, Wh_bf, b_h2h,
                                           c2, hs, inp_bf, proj_bf, x_bf, W_score,
                                           pc, pm, ps, -1);
    for (int t = 0; t < T_; ++t) {
        z_gemm<<<dim3(32), 512, 0, stream>>>(inp_bf, WU_t, pc, pm, ps, z_buf);
        ghp_e2<<<dim3(256), 1024, 0, stream>>>(z_buf, text, W_lstm, b_lstm, Wh_bf, b_h2h,
                                               c2, hs + (size_t)t * (B_ * H_),
                                               inp_bf, proj_bf, x_bf, W_score,
                                               pc, pm, ps, t);
    }
    gen_probs<<<dim3(400), 64, 0, stream>>>(hs, W_gen, b_gen, out);
}

// Round 14
// 1417.637 us; speedup vs baseline: 1.0411x; 1.0411x over previous
//
#include <hip/hip_runtime.h>
#include <hip/hip_bf16.h>

#define B_ 128
#define S_ 512
#define C_ 512
#define H_ 512
#define NC_ 64
#define T_ 25
#define TEXTW (T_ + 1)

typedef __attribute__((ext_vector_type(8))) short bf16x8;
typedef __attribute__((ext_vector_type(8))) unsigned short u16x8;
typedef __attribute__((ext_vector_type(4))) float f32x4;

__device__ __forceinline__ float bf2f(unsigned short u) {
    union { unsigned int i; float f; } v; v.i = ((unsigned int)u) << 16; return v.f;
}
__device__ __forceinline__ unsigned short f2bf(float f) {
    union { float f; unsigned int u; } v; v.f = f;
    unsigned int r = (v.u + 0x7FFFu + ((v.u >> 16) & 1u)) >> 16;
    return (unsigned short)r;
}
__device__ __forceinline__ void gload_lds16(const void* g, void* l) {
    __builtin_amdgcn_global_load_lds(
        (const __attribute__((address_space(1))) unsigned int*)g,
        (__attribute__((address_space(3))) unsigned int*)l, 16, 0, 0);
}
__device__ __forceinline__ float fast_tanh(float x) {
    float e = __builtin_amdgcn_exp2f(2.885390082f * x);
    return 1.f - 2.f * __builtin_amdgcn_rcpf(e + 1.f);
}
__device__ __forceinline__ float fast_sigmoid(float x) {
    return __builtin_amdgcn_rcpf(1.f + __builtin_amdgcn_exp2f(-1.442695041f * x));
}

// ---------------- setup: init state + all weight conversions ----------------
__global__ __launch_bounds__(512) void setup_k(
    const float* __restrict__ Wi, const float* __restrict__ Wh,
    const float* __restrict__ Wl, const float* __restrict__ Ul,
    unsigned short* __restrict__ Wt_bf, unsigned short* __restrict__ Wh_bf,
    unsigned short* __restrict__ WU_t,
    float* __restrict__ c2, unsigned short* __restrict__ inp) {
    int blk = blockIdx.x, tid = threadIdx.x;
    if (blk < 128) {
        c2[blk * 512 + tid] = 0.f;
        c2[65536 + blk * 512 + tid] = 0.f;
        inp[blk * 1024 + 512 + tid] = 0;
    } else if (blk < 640) {
        int n = blk - 128;
        Wt_bf[n * 512 + tid] = f2bf(Wi[tid * 512 + n]);
    } else if (blk < 1152) {
        int i = (blk - 640) * 512 + tid;
        Wh_bf[i] = f2bf(Wh[i]);
    } else {
        int np = blk - 1152;
        int h = np >> 2, g = np & 3;
        {
            float v = Wl[(size_t)tid * 2048 + g * 512 + h];
            WU_t[(size_t)np * 1024 + tid] = f2bf(v);
        }
        {
            float v = Ul[(size_t)tid * 2048 + g * 512 + h];
            WU_t[(size_t)np * 1024 + 512 + tid] = f2bf(v);
        }
    }
}

// ---------------- x f32 -> bf16 ----------------
__global__ __launch_bounds__(256) void conv_x(const float* __restrict__ in,
                                              unsigned short* __restrict__ out) {
    int i = blockIdx.x * 256 + threadIdx.x;
    const float4 v = ((const float4*)in)[i];
    ushort4 o;
    o.x = f2bf(v.x); o.y = f2bf(v.y); o.z = f2bf(v.z); o.w = f2bf(v.w);
    ((ushort4*)out)[i] = o;
}

// ---------------- proj = x @ W_i2h via MFMA (bf16) ----------------
__global__ __launch_bounds__(256) void gemm_proj(const unsigned short* __restrict__ A,
                                                 const unsigned short* __restrict__ Bt,
                                                 unsigned short* __restrict__ Cm) {
    __shared__ unsigned short As[128 * 64];
    __shared__ unsigned short Bs[128 * 64];
    int tid = threadIdx.x;
    int lane = tid & 63;
    int wid = tid >> 6;
    int wr = wid >> 1, wc = wid & 1;
    int row0 = blockIdx.y * 128;
    int col0 = blockIdx.x * 128;

    f32x4 acc[4][4];
#pragma unroll
    for (int i = 0; i < 4; ++i)
#pragma unroll
        for (int j = 0; j < 4; ++j) acc[i][j] = (f32x4){0.f, 0.f, 0.f, 0.f};

    for (int k0 = 0; k0 < 512; k0 += 64) {
#pragma unroll
        for (int i = 0; i < 4; ++i) {
            int e = tid + i * 256;
            int r = e >> 3, cc = e & 7;
            int cs = cc ^ (r & 7);
            gload_lds16(A + (size_t)(row0 + r) * 512 + k0 + cs * 8, &As[e * 8]);
        }
#pragma unroll
        for (int i = 0; i < 4; ++i) {
            int e = tid + i * 256;
            int r = e >> 3, cc = e & 7;
            int cs = cc ^ (r & 7);
            gload_lds16(Bt + (size_t)(col0 + r) * 512 + k0 + cs * 8, &Bs[e * 8]);
        }
        __syncthreads();
#pragma unroll
        for (int ks = 0; ks < 2; ++ks) {
            bf16x8 a[4], b[4];
#pragma unroll
            for (int i = 0; i < 4; ++i) {
                int m = wr * 64 + i * 16 + (lane & 15);
                int ch = (ks * 4 + (lane >> 4)) ^ (m & 7);
                a[i] = *(const bf16x8*)&As[(m * 8 + ch) * 8];
            }
#pragma unroll
            for (int j = 0; j < 4; ++j) {
                int n = wc * 64 + j * 16 + (lane & 15);
                int ch = (ks * 4 + (lane >> 4)) ^ (n & 7);
                b[j] = *(const bf16x8*)&Bs[(n * 8 + ch) * 8];
            }
#pragma unroll
            for (int i = 0; i < 4; ++i)
#pragma unroll
                for (int j = 0; j < 4; ++j)
                    acc[i][j] = __builtin_amdgcn_mfma_f32_16x16x32_bf16(a[i], b[j], acc[i][j], 0, 0, 0);
        }
        __syncthreads();
    }
#pragma unroll
    for (int i = 0; i < 4; ++i)
#pragma unroll
        for (int j = 0; j < 4; ++j) {
            int gcol = col0 + wc * 64 + j * 16 + (lane & 15);
#pragma unroll
            for (int r = 0; r < 4; ++r) {
                int grow = row0 + wr * 64 + i * 16 + (lane >> 4) * 4 + r;
                Cm[(size_t)grow * 512 + gcol] = f2bf(acc[i][j][r]);
            }
        }
}

// ---------------- z = [ctx|h] @ WU_t^T; 32 blocks x 512 thr; BK=128 ----------------
__global__ __launch_bounds__(512) void z_gemm(
    const unsigned short* __restrict__ inp, const unsigned short* __restrict__ Bt,
    const float* __restrict__ pc, const float* __restrict__ pm,
    const float* __restrict__ ps, float* __restrict__ Z) {
    __shared__ unsigned short As[128 * 128];   // 32 KB
    __shared__ unsigned short Bs[64 * 128];    // 16 KB
    int tid = threadIdx.x;
    int lane = tid & 63;
    int wave = tid >> 6;
    int wr = wave >> 2, wc = wave & 3;
    int col0 = blockIdx.x * 64;

    float cw0[4], cw1[4];
    int rr[4], csv[4];
#pragma unroll
    for (int i = 0; i < 4; ++i) {
        int e = tid + i * 512;
        int r = e >> 4, cc = e & 15;
        rr[i] = r; csv[i] = cc ^ (r & 15);
        float m0 = pm[r], m1 = pm[128 + r];
        float s0 = ps[r], s1 = ps[128 + r];
        float M = fmaxf(m0, m1);
        float w0 = __builtin_amdgcn_exp2f(1.442695041f * (m0 - M));
        float w1 = __builtin_amdgcn_exp2f(1.442695041f * (m1 - M));
        float inv = 1.f / (w0 * s0 + w1 * s1);
        cw0[i] = w0 * inv; cw1[i] = w1 * inv;
    }

    f32x4 acc[4];
#pragma unroll
    for (int i = 0; i < 4; ++i) acc[i] = (f32x4){0.f, 0.f, 0.f, 0.f};

    for (int k0 = 0; k0 < 1024; k0 += 128) {
        if (k0 < 512) {
#pragma unroll
            for (int i = 0; i < 4; ++i) {
                int e = tid + i * 512;
                int kb = k0 + csv[i] * 8;
                const float* c0p = pc + rr[i] * 512 + kb;
                const float* c1p = pc + 65536 + rr[i] * 512 + kb;
                float4 c0a = *(const float4*)c0p;
                float4 c0b = *(const float4*)(c0p + 4);
                float4 c1a = *(const float4*)c1p;
                float4 c1b = *(const float4*)(c1p + 4);
                u16x8 o;
                o[0] = f2bf(cw0[i] * c0a.x + cw1[i] * c1a.x);
                o[1] = f2bf(cw0[i] * c0a.y + cw1[i] * c1a.y);
                o[2] = f2bf(cw0[i] * c0a.z + cw1[i] * c1a.z);
                o[3] = f2bf(cw0[i] * c0a.w + cw1[i] * c1a.w);
                o[4] = f2bf(cw0[i] * c0b.x + cw1[i] * c1b.x);
                o[5] = f2bf(cw0[i] * c0b.y + cw1[i] * c1b.y);
                o[6] = f2bf(cw0[i] * c0b.z + cw1[i] * c1b.z);
                o[7] = f2bf(cw0[i] * c0b.w + cw1[i] * c1b.w);
                *(u16x8*)&As[e * 8] = o;
            }
        } else {
#pragma unroll
            for (int i = 0; i < 4; ++i) {
                int e = tid + i * 512;
                gload_lds16(inp + (size_t)rr[i] * 1024 + k0 + csv[i] * 8, &As[e * 8]);
            }
        }
#pragma unroll
        for (int i = 0; i < 2; ++i) {
            int e = tid + i * 512;
            int r = e >> 4, cc = e & 15;
            int cs = cc ^ (r & 15);
            gload_lds16(Bt + (size_t)(col0 + r) * 1024 + k0 + cs * 8, &Bs[e * 8]);
        }
        __syncthreads();
#pragma unroll
        for (int ks = 0; ks < 4; ++ks) {
            bf16x8 a[4], bfr;
#pragma unroll
            for (int i = 0; i < 4; ++i) {
                int m = wr * 64 + i * 16 + (lane & 15);
                int ch = (ks * 4 + (lane >> 4)) ^ (m & 15);
                a[i] = *(const bf16x8*)&As[(m * 16 + ch) * 8];
            }
            {
                int n = wc * 16 + (lane & 15);
                int ch = (ks * 4 + (lane >> 4)) ^ (n & 15);
                bfr = *(const bf16x8*)&Bs[(n * 16 + ch) * 8];
            }
#pragma unroll
            for (int i = 0; i < 4; ++i)
                acc[i] = __builtin_amdgcn_mfma_f32_16x16x32_bf16(a[i], bfr, acc[i], 0, 0, 0);
        }
        __syncthreads();
    }
#pragma unroll
    for (int i = 0; i < 4; ++i) {
        int gcol = col0 + wc * 16 + (lane & 15);
#pragma unroll
        for (int r = 0; r < 4; ++r) {
            int grow = wr * 64 + i * 16 + (lane >> 4) * 4 + r;
            Z[(size_t)grow * 2048 + gcol] = acc[i][r];
        }
    }
}

// ---------------- fused: gates(t)+hp(t) [dup per half] + E/partial-softmax/partial-ctx(t+1) ----------------
// 256 blocks = (half, b); 1024 threads. t==-1: ectx only. t==24: gates only.
__global__ __launch_bounds__(1024) void ghp_e2(
    const float* __restrict__ z, const int* __restrict__ text,
    const float* __restrict__ Wl, const float* __restrict__ bl,
    const unsigned short* __restrict__ Whb, const float* __restrict__ bh2h,
    float* __restrict__ c2, float* __restrict__ hs_t,
    unsigned short* __restrict__ inp,
    const unsigned short* __restrict__ proj, const unsigned short* __restrict__ xb,
    const float* __restrict__ Wscore,
    float* __restrict__ pc, float* __restrict__ pm, float* __restrict__ ps, int t) {
    __shared__ float shg[512];
    __shared__ float wk[16][512];   // hp partials, then ctx partials
    __shared__ float sh_hp[512];
    __shared__ float sh_e[256];
    __shared__ float sh_alpha[256];
    __shared__ float sh_red[8];
    int blk = blockIdx.x;
    int half = blk >> 7, b = blk & 127;
    int tid = threadIdx.x, wave = tid >> 6, lane = tid & 63;

    if (t >= 0) {
        // ---- gates (duplicated per half; each half owns its c copy) ----
        if (tid < 512) {
            int ch = text[b * TEXTW + t];
            const float* wrow = Wl + (size_t)(512 + ch) * 2048;
            float4 zv = *(const float4*)(z + (size_t)b * 2048 + tid * 4);
            float zi = zv.x + bl[tid] + wrow[tid];
            float zf = zv.y + bl[512 + tid] + wrow[512 + tid];
            float zg = zv.z + bl[1024 + tid] + wrow[1024 + tid];
            float zo = zv.w + bl[1536 + tid] + wrow[1536 + tid];
            float ig = fast_sigmoid(zi);
            float fg = fast_sigmoid(zf);
            float gg = fast_tanh(zg);
            float og = fast_sigmoid(zo);
            int idx = half * 65536 + b * 512 + tid;
            float cn = fg * c2[idx] + ig * gg;
            c2[idx] = cn;
            float hn = og * fast_tanh(cn);
            if (half == 0) {
                hs_t[b * 512 + tid] = hn;
                inp[b * 1024 + 512 + tid] = f2bf(hn);
            }
            shg[tid] = hn;
        }
        __syncthreads();
        if (t >= T_ - 1) return;
        // ---- hp (full GEMV, duplicated per half); wave owns 32 k, lane owns 8 cols ----
        {
            float r8[8] = {0.f, 0.f, 0.f, 0.f, 0.f, 0.f, 0.f, 0.f};
#pragma unroll 4
            for (int kk = 0; kk < 32; ++kk) {
                int k = wave * 32 + kk;
                float hv = shg[k];
                u16x8 wv = *(const u16x8*)(Whb + k * 512 + lane * 8);
#pragma unroll
                for (int jj = 0; jj < 8; ++jj) r8[jj] = fmaf(hv, bf2f(wv[jj]), r8[jj]);
            }
#pragma unroll
            for (int jj = 0; jj < 8; ++jj) wk[wave][lane * 8 + jj] = r8[jj];
        }
        __syncthreads();
        if (tid < 512) {
            float s = bh2h[tid];
#pragma unroll
            for (int w = 0; w < 16; ++w) s += wk[w][tid];
            sh_hp[tid] = s;
        }
        __syncthreads();
    } else {
        if (tid < 512) sh_hp[tid] = bh2h[tid];
        __syncthreads();
    }

    // ---- E over this half's 256 s-rows; wave owns 16, 4-row prefetch ----
    {
        float4 h0 = *(const float4*)(sh_hp + lane * 8);
        float4 h1 = *(const float4*)(sh_hp + lane * 8 + 4);
        float4 w0 = *(const float4*)(Wscore + lane * 8);
        float4 w1 = *(const float4*)(Wscore + lane * 8 + 4);
        float hp_r[8] = {h0.x, h0.y, h0.z, h0.w, h1.x, h1.y, h1.z, h1.w};
        float w_r[8]  = {w0.x, w0.y, w0.z, w0.w, w1.x, w1.y, w1.z, w1.w};
        float w2_r[8];
#pragma unroll
        for (int j = 0; j < 8; ++j) w2_r[j] = -2.f * w_r[j];
        int s0g = half * 256 + wave * 16;
        for (int i = 0; i < 16; i += 4) {
            bf16x8 pv[4];
#pragma unroll
            for (int q = 0; q < 4; ++q)
                pv[q] = *(const bf16x8*)(proj + ((size_t)(b * 512 + s0g + i + q) << 9) + lane * 8);
#pragma unroll
            for (int q = 0; q < 4; ++q) {
                float a = 0.f;
#pragma unroll
                for (int j = 0; j < 8; ++j) {
                    float xv = bf2f((unsigned short)pv[q][j]) + hp_r[j];
                    float r = __builtin_amdgcn_rcpf(__builtin_amdgcn_exp2f(2.885390082f * xv) + 1.f);
                    a += w_r[j];
                    a = fmaf(w2_r[j], r, a);
                }
#pragma unroll
                for (int off = 32; off > 0; off >>= 1) a += __shfl_xor(a, off, 64);
                if (lane == 0) sh_e[wave * 16 + i + q] = a;
            }
        }
    }
    __syncthreads();

    // ---- partial softmax over 256 (waves 0..3) ----
    if (tid < 256) {
        float v = sh_e[tid];
        float m = v;
#pragma unroll
        for (int off = 32; off > 0; off >>= 1) m = fmaxf(m, __shfl_xor(m, off, 64));
        if (lane == 0) sh_red[wave] = m;
    }
    __syncthreads();
    if (tid < 256) {
        float mh = fmaxf(fmaxf(sh_red[0], sh_red[1]), fmaxf(sh_red[2], sh_red[3]));
        float p = __builtin_amdgcn_exp2f(1.442695041f * (sh_e[tid] - mh));
        float ss = p;
#pragma unroll
        for (int off = 32; off > 0; off >>= 1) ss += __shfl_xor(ss, off, 64);
        if (lane == 0) sh_red[4 + wave] = ss;
        sh_alpha[tid] = p;
    }
    __syncthreads();
    if (tid == 0) {
        pm[half * 128 + b] = fmaxf(fmaxf(sh_red[0], sh_red[1]), fmaxf(sh_red[2], sh_red[3]));
        ps[half * 128 + b] = sh_red[4] + sh_red[5] + sh_red[6] + sh_red[7];
    }

    // ---- partial context: wave owns s-group (16 of them), lane owns 8 contiguous cols ----
    {
        int j0 = lane * 8;
        float a[8] = {0.f, 0.f, 0.f, 0.f, 0.f, 0.f, 0.f, 0.f};
        for (int sl = wave; sl < 256; sl += 16) {
            float al = sh_alpha[sl];
            int s = half * 256 + sl;
            u16x8 xv = *(const u16x8*)(xb + ((size_t)(b * 512 + s) << 9) + j0);
#pragma unroll
            for (int j = 0; j < 8; ++j) a[j] = fmaf(al, bf2f(xv[j]), a[j]);
        }
#pragma unroll
        for (int j = 0; j < 8; ++j) wk[wave][j0 + j] = a[j];
    }
    __syncthreads();
    if (tid < 512) {
        float s = 0.f;
#pragma unroll
        for (int w = 0; w < 16; ++w) s += wk[w][tid];
        pc[(size_t)(half * 128 + b) * 512 + tid] = s;
    }
}

// ---------------- probs = hs @ W_gen + b_gen; 400 blocks x 64 thr, 8 rows/block ----------------
__global__ __launch_bounds__(64) void gen_probs(const float* __restrict__ hs,
                                                const float* __restrict__ Wg,
                                                const float* __restrict__ bg,
                                                float* __restrict__ out) {
    __shared__ float sh[8][512];
    int r0 = blockIdx.x * 8;
    int tid = threadIdx.x;
#pragma unroll
    for (int q = 0; q < 8; ++q) {
        int row = r0 + q;
        int b = row / T_, t = row % T_;
        const float* hrow = hs + ((size_t)t * B_ + b) * H_;
        for (int i = tid; i < 512; i += 64) sh[q][i] = hrow[i];
    }
    __syncthreads();
    float acc[8];
#pragma unroll
    for (int q = 0; q < 8; ++q) acc[q] = bg[tid];
#pragma unroll 4
    for (int k = 0; k < 512; ++k) {
        float w = Wg[k * 64 + tid];
#pragma unroll
        for (int q = 0; q < 8; ++q) acc[q] = fmaf(sh[q][k], w, acc[q]);
    }
#pragma unroll
    for (int q = 0; q < 8; ++q) out[(size_t)(r0 + q) * 64 + tid] = acc[q];
}

extern "C" void kernel_launch(void* const* d_in, const int* in_sizes, int n_in,
                              void* d_out, int out_size, void* d_ws, size_t ws_size,
                              hipStream_t stream) {
    const float* x       = (const float*)d_in[0];
    const int*   text    = (const int*)d_in[1];
    const float* W_i2h   = (const float*)d_in[2];
    const float* W_h2h   = (const float*)d_in[3];
    const float* b_h2h   = (const float*)d_in[4];
    const float* W_score = (const float*)d_in[5];
    const float* W_lstm  = (const float*)d_in[6];
    const float* U_lstm  = (const float*)d_in[7];
    const float* b_lstm  = (const float*)d_in[8];
    const float* W_gen   = (const float*)d_in[9];
    const float* b_gen   = (const float*)d_in[10];
    float* out = (float*)d_out;

    char* ws = (char*)d_ws;
    unsigned short* x_bf    = (unsigned short*)ws;                 // 67,108,864
    unsigned short* proj_bf = (unsigned short*)(ws + 67108864);    // 67,108,864
    unsigned short* Wt_bf   = (unsigned short*)(ws + 134217728);   //    524,288
    unsigned short* Wh_bf   = (unsigned short*)(ws + 134742016);   //    524,288
    unsigned short* WU_t    = (unsigned short*)(ws + 135266304);   //  4,194,304
    float* c2      = (float*)(ws + 139460608);                     //    524,288 (2 copies)
    unsigned short* inp_bf = (unsigned short*)(ws + 139984896);    //    262,144
    float* z_buf   = (float*)(ws + 140247040);                     //  1,048,576
    float* pc      = (float*)(ws + 141295616);                     //    524,288
    float* pm      = (float*)(ws + 141819904);                     //      1,024
    float* ps      = (float*)(ws + 141820928);                     //      1,024
    float* hs      = (float*)(ws + 141821952);                     // 13,107,200

    setup_k<<<dim3(3200), 512, 0, stream>>>(W_i2h, W_h2h, W_lstm, U_lstm,
                                            Wt_bf, Wh_bf, WU_t, c2, inp_bf);
    conv_x<<<dim3(32768), 256, 0, stream>>>(x, x_bf);
    gemm_proj<<<dim3(4, 512), 256, 0, stream>>>(x_bf, Wt_bf, proj_bf);
    // partial ectx for t=0 with hp = b_h2h
    ghp_e2<<<dim3(256), 1024, 0, stream>>>(z_buf, text, W_lstm, b_lstm, Wh_bf, b_h2h,
                                           c2, hs, inp_bf, proj_bf, x_bf, W_score,
                                           pc, pm, ps, -1);
    for (int t = 0; t < T_; ++t) {
        z_gemm<<<dim3(32), 512, 0, stream>>>(inp_bf, WU_t, pc, pm, ps, z_buf);
        ghp_e2<<<dim3(256), 1024, 0, stream>>>(z_buf, text, W_lstm, b_lstm, Wh_bf, b_h2h,
                                               c2, hs + (size_t)t * (B_ * H_),
                                               inp_bf, proj_bf, x_bf, W_score,
                                               pc, pm, ps, t);
    }
    gen_probs<<<dim3(400), 64, 0, stream>>>(hs, W_gen, b_gen, out);
}

// Round 15
// 1398.961 us; speedup vs baseline: 1.0550x; 1.0133x over previous
//
#include <hip/hip_runtime.h>
#include <hip/hip_bf16.h>

#define B_ 128
#define S_ 512
#define C_ 512
#define H_ 512
#define NC_ 64
#define T_ 25
#define TEXTW (T_ + 1)

typedef __attribute__((ext_vector_type(8))) short bf16x8;
typedef __attribute__((ext_vector_type(8))) unsigned short u16x8;
typedef __attribute__((ext_vector_type(4))) float f32x4;

__device__ __forceinline__ float bf2f(unsigned short u) {
    union { unsigned int i; float f; } v; v.i = ((unsigned int)u) << 16; return v.f;
}
__device__ __forceinline__ unsigned short f2bf(float f) {
    union { float f; unsigned int u; } v; v.f = f;
    unsigned int r = (v.u + 0x7FFFu + ((v.u >> 16) & 1u)) >> 16;
    return (unsigned short)r;
}
__device__ __forceinline__ void gload_lds16(const void* g, void* l) {
    __builtin_amdgcn_global_load_lds(
        (const __attribute__((address_space(1))) unsigned int*)g,
        (__attribute__((address_space(3))) unsigned int*)l, 16, 0, 0);
}
__device__ __forceinline__ float fast_tanh(float x) {
    float e = __builtin_amdgcn_exp2f(2.885390082f * x);
    return 1.f - 2.f * __builtin_amdgcn_rcpf(e + 1.f);
}
__device__ __forceinline__ float fast_sigmoid(float x) {
    return __builtin_amdgcn_rcpf(1.f + __builtin_amdgcn_exp2f(-1.442695041f * x));
}

// ---------------- setup: init state + all weight conversions ----------------
__global__ __launch_bounds__(512) void setup_k(
    const float* __restrict__ Wi, const float* __restrict__ Wh,
    const float* __restrict__ Wl, const float* __restrict__ Ul,
    unsigned short* __restrict__ Wt_bf, unsigned short* __restrict__ Wh_bf,
    unsigned short* __restrict__ WU_t,
    float* __restrict__ c2, unsigned short* __restrict__ inp) {
    int blk = blockIdx.x, tid = threadIdx.x;
    if (blk < 128) {
        c2[blk * 512 + tid] = 0.f;
        c2[65536 + blk * 512 + tid] = 0.f;
        inp[blk * 1024 + 512 + tid] = 0;
    } else if (blk < 640) {
        int n = blk - 128;
        Wt_bf[n * 512 + tid] = f2bf(Wi[tid * 512 + n]);
    } else if (blk < 1152) {
        int i = (blk - 640) * 512 + tid;
        Wh_bf[i] = f2bf(Wh[i]);
    } else {
        int np = blk - 1152;
        int h = np >> 2, g = np & 3;
        {
            float v = Wl[(size_t)tid * 2048 + g * 512 + h];
            WU_t[(size_t)np * 1024 + tid] = f2bf(v);
        }
        {
            float v = Ul[(size_t)tid * 2048 + g * 512 + h];
            WU_t[(size_t)np * 1024 + 512 + tid] = f2bf(v);
        }
    }
}

// ---------------- x f32 -> bf16 ----------------
__global__ __launch_bounds__(256) void conv_x(const float* __restrict__ in,
                                              unsigned short* __restrict__ out) {
    int i = blockIdx.x * 256 + threadIdx.x;
    const float4 v = ((const float4*)in)[i];
    ushort4 o;
    o.x = f2bf(v.x); o.y = f2bf(v.y); o.z = f2bf(v.z); o.w = f2bf(v.w);
    ((ushort4*)out)[i] = o;
}

// ---------------- proj = x @ W_i2h via MFMA (bf16) ----------------
__global__ __launch_bounds__(256) void gemm_proj(const unsigned short* __restrict__ A,
                                                 const unsigned short* __restrict__ Bt,
                                                 unsigned short* __restrict__ Cm) {
    __shared__ unsigned short As[128 * 64];
    __shared__ unsigned short Bs[128 * 64];
    int tid = threadIdx.x;
    int lane = tid & 63;
    int wid = tid >> 6;
    int wr = wid >> 1, wc = wid & 1;
    int row0 = blockIdx.y * 128;
    int col0 = blockIdx.x * 128;

    f32x4 acc[4][4];
#pragma unroll
    for (int i = 0; i < 4; ++i)
#pragma unroll
        for (int j = 0; j < 4; ++j) acc[i][j] = (f32x4){0.f, 0.f, 0.f, 0.f};

    for (int k0 = 0; k0 < 512; k0 += 64) {
#pragma unroll
        for (int i = 0; i < 4; ++i) {
            int e = tid + i * 256;
            int r = e >> 3, cc = e & 7;
            int cs = cc ^ (r & 7);
            gload_lds16(A + (size_t)(row0 + r) * 512 + k0 + cs * 8, &As[e * 8]);
        }
#pragma unroll
        for (int i = 0; i < 4; ++i) {
            int e = tid + i * 256;
            int r = e >> 3, cc = e & 7;
            int cs = cc ^ (r & 7);
            gload_lds16(Bt + (size_t)(col0 + r) * 512 + k0 + cs * 8, &Bs[e * 8]);
        }
        __syncthreads();
#pragma unroll
        for (int ks = 0; ks < 2; ++ks) {
            bf16x8 a[4], b[4];
#pragma unroll
            for (int i = 0; i < 4; ++i) {
                int m = wr * 64 + i * 16 + (lane & 15);
                int ch = (ks * 4 + (lane >> 4)) ^ (m & 7);
                a[i] = *(const bf16x8*)&As[(m * 8 + ch) * 8];
            }
#pragma unroll
            for (int j = 0; j < 4; ++j) {
                int n = wc * 64 + j * 16 + (lane & 15);
                int ch = (ks * 4 + (lane >> 4)) ^ (n & 7);
                b[j] = *(const bf16x8*)&Bs[(n * 8 + ch) * 8];
            }
#pragma unroll
            for (int i = 0; i < 4; ++i)
#pragma unroll
                for (int j = 0; j < 4; ++j)
                    acc[i][j] = __builtin_amdgcn_mfma_f32_16x16x32_bf16(a[i], b[j], acc[i][j], 0, 0, 0);
        }
        __syncthreads();
    }
#pragma unroll
    for (int i = 0; i < 4; ++i)
#pragma unroll
        for (int j = 0; j < 4; ++j) {
            int gcol = col0 + wc * 64 + j * 16 + (lane & 15);
#pragma unroll
            for (int r = 0; r < 4; ++r) {
                int grow = row0 + wr * 64 + i * 16 + (lane >> 4) * 4 + r;
                Cm[(size_t)grow * 512 + gcol] = f2bf(acc[i][j][r]);
            }
        }
}

// ---------------- z = [ctx|h] @ WU_t^T; 32 blocks x 512 thr; BK=128 ----------------
__global__ __launch_bounds__(512) void z_gemm(
    const unsigned short* __restrict__ inp, const unsigned short* __restrict__ Bt,
    const float* __restrict__ pc, const float* __restrict__ pm,
    const float* __restrict__ ps, float* __restrict__ Z) {
    __shared__ unsigned short As[128 * 128];   // 32 KB
    __shared__ unsigned short Bs[64 * 128];    // 16 KB
    int tid = threadIdx.x;
    int lane = tid & 63;
    int wave = tid >> 6;
    int wr = wave >> 2, wc = wave & 3;
    int col0 = blockIdx.x * 64;

    float cw0[4], cw1[4];
    int rr[4], csv[4];
#pragma unroll
    for (int i = 0; i < 4; ++i) {
        int e = tid + i * 512;
        int r = e >> 4, cc = e & 15;
        rr[i] = r; csv[i] = cc ^ (r & 15);
        float m0 = pm[r], m1 = pm[128 + r];
        float s0 = ps[r], s1 = ps[128 + r];
        float M = fmaxf(m0, m1);
        float w0 = __builtin_amdgcn_exp2f(1.442695041f * (m0 - M));
        float w1 = __builtin_amdgcn_exp2f(1.442695041f * (m1 - M));
        float inv = 1.f / (w0 * s0 + w1 * s1);
        cw0[i] = w0 * inv; cw1[i] = w1 * inv;
    }

    f32x4 acc[4];
#pragma unroll
    for (int i = 0; i < 4; ++i) acc[i] = (f32x4){0.f, 0.f, 0.f, 0.f};

    for (int k0 = 0; k0 < 1024; k0 += 128) {
        if (k0 < 512) {
#pragma unroll
            for (int i = 0; i < 4; ++i) {
                int e = tid + i * 512;
                int kb = k0 + csv[i] * 8;
                const float* c0p = pc + rr[i] * 512 + kb;
                const float* c1p = pc + 65536 + rr[i] * 512 + kb;
                float4 c0a = *(const float4*)c0p;
                float4 c0b = *(const float4*)(c0p + 4);
                float4 c1a = *(const float4*)c1p;
                float4 c1b = *(const float4*)(c1p + 4);
                u16x8 o;
                o[0] = f2bf(cw0[i] * c0a.x + cw1[i] * c1a.x);
                o[1] = f2bf(cw0[i] * c0a.y + cw1[i] * c1a.y);
                o[2] = f2bf(cw0[i] * c0a.z + cw1[i] * c1a.z);
                o[3] = f2bf(cw0[i] * c0a.w + cw1[i] * c1a.w);
                o[4] = f2bf(cw0[i] * c0b.x + cw1[i] * c1b.x);
                o[5] = f2bf(cw0[i] * c0b.y + cw1[i] * c1b.y);
                o[6] = f2bf(cw0[i] * c0b.z + cw1[i] * c1b.z);
                o[7] = f2bf(cw0[i] * c0b.w + cw1[i] * c1b.w);
                *(u16x8*)&As[e * 8] = o;
            }
        } else {
#pragma unroll
            for (int i = 0; i < 4; ++i) {
                int e = tid + i * 512;
                gload_lds16(inp + (size_t)rr[i] * 1024 + k0 + csv[i] * 8, &As[e * 8]);
            }
        }
#pragma unroll
        for (int i = 0; i < 2; ++i) {
            int e = tid + i * 512;
            int r = e >> 4, cc = e & 15;
            int cs = cc ^ (r & 15);
            gload_lds16(Bt + (size_t)(col0 + r) * 1024 + k0 + cs * 8, &Bs[e * 8]);
        }
        __syncthreads();
#pragma unroll
        for (int ks = 0; ks < 4; ++ks) {
            bf16x8 a[4], bfr;
#pragma unroll
            for (int i = 0; i < 4; ++i) {
                int m = wr * 64 + i * 16 + (lane & 15);
                int ch = (ks * 4 + (lane >> 4)) ^ (m & 15);
                a[i] = *(const bf16x8*)&As[(m * 16 + ch) * 8];
            }
            {
                int n = wc * 16 + (lane & 15);
                int ch = (ks * 4 + (lane >> 4)) ^ (n & 15);
                bfr = *(const bf16x8*)&Bs[(n * 16 + ch) * 8];
            }
#pragma unroll
            for (int i = 0; i < 4; ++i)
                acc[i] = __builtin_amdgcn_mfma_f32_16x16x32_bf16(a[i], bfr, acc[i], 0, 0, 0);
        }
        __syncthreads();
    }
#pragma unroll
    for (int i = 0; i < 4; ++i) {
        int gcol = col0 + wc * 16 + (lane & 15);
#pragma unroll
        for (int r = 0; r < 4; ++r) {
            int grow = wr * 64 + i * 16 + (lane >> 4) * 4 + r;
            Z[(size_t)grow * 2048 + gcol] = acc[i][r];
        }
    }
}

// ---------------- fused: gates(t)+hp(t) [dup per half] + E/partial-softmax/partial-ctx(t+1) ----------------
// 256 blocks = (half, b); 1024 threads. t==-1: ectx only. t==24: gates only.
__global__ __launch_bounds__(1024) void ghp_e2(
    const float* __restrict__ z, const int* __restrict__ text,
    const float* __restrict__ Wl, const float* __restrict__ bl,
    const unsigned short* __restrict__ Whb, const float* __restrict__ bh2h,
    float* __restrict__ c2, float* __restrict__ hs_t,
    unsigned short* __restrict__ inp,
    const unsigned short* __restrict__ proj, const unsigned short* __restrict__ xb,
    const float* __restrict__ Wscore,
    float* __restrict__ pc, float* __restrict__ pm, float* __restrict__ ps, int t) {
    __shared__ float shg[512];
    __shared__ float gp[16][512];
    __shared__ float sh_hp[512];
    __shared__ float sh_e[256];
    __shared__ float sh_alpha[256];
    __shared__ float sh_red[8];
    __shared__ float shp[8][512];
    int blk = blockIdx.x;
    int half = blk >> 7, b = blk & 127;
    int tid = threadIdx.x, wave = tid >> 6, lane = tid & 63;

    if (t >= 0) {
        // ---- gates (duplicated per half; each half owns its c copy) ----
        if (tid < 512) {
            int ch = text[b * TEXTW + t];
            const float* wrow = Wl + (size_t)(512 + ch) * 2048;
            float4 zv = *(const float4*)(z + (size_t)b * 2048 + tid * 4);
            float zi = zv.x + bl[tid] + wrow[tid];
            float zf = zv.y + bl[512 + tid] + wrow[512 + tid];
            float zg = zv.z + bl[1024 + tid] + wrow[1024 + tid];
            float zo = zv.w + bl[1536 + tid] + wrow[1536 + tid];
            float ig = fast_sigmoid(zi);
            float fg = fast_sigmoid(zf);
            float gg = fast_tanh(zg);
            float og = fast_sigmoid(zo);
            int idx = half * 65536 + b * 512 + tid;
            float cn = fg * c2[idx] + ig * gg;
            c2[idx] = cn;
            float hn = og * fast_tanh(cn);
            if (half == 0) {
                hs_t[b * 512 + tid] = hn;
                inp[b * 1024 + 512 + tid] = f2bf(hn);
            }
            shg[tid] = hn;
        }
        __syncthreads();
        if (t >= T_ - 1) return;
        // ---- hp (full GEMV, duplicated per half); wave owns 32 k, lane owns 8 cols ----
        {
            float r8[8] = {0.f, 0.f, 0.f, 0.f, 0.f, 0.f, 0.f, 0.f};
#pragma unroll 4
            for (int kk = 0; kk < 32; ++kk) {
                int k = wave * 32 + kk;
                float hv = shg[k];
                u16x8 wv = *(const u16x8*)(Whb + k * 512 + lane * 8);
#pragma unroll
                for (int jj = 0; jj < 8; ++jj) r8[jj] = fmaf(hv, bf2f(wv[jj]), r8[jj]);
            }
#pragma unroll
            for (int jj = 0; jj < 8; ++jj) gp[wave][lane * 8 + jj] = r8[jj];
        }
        __syncthreads();
        if (tid < 512) {
            float s = bh2h[tid];
#pragma unroll
            for (int w = 0; w < 16; ++w) s += gp[w][tid];
            sh_hp[tid] = s;
        }
        __syncthreads();
    } else {
        if (tid < 512) sh_hp[tid] = bh2h[tid];
        __syncthreads();
    }

    // ---- E over this half's 256 s-rows; wave owns 16, 4-row prefetch ----
    {
        float4 h0 = *(const float4*)(sh_hp + lane * 8);
        float4 h1 = *(const float4*)(sh_hp + lane * 8 + 4);
        float4 w0 = *(const float4*)(Wscore + lane * 8);
        float4 w1 = *(const float4*)(Wscore + lane * 8 + 4);
        float hp_r[8] = {h0.x, h0.y, h0.z, h0.w, h1.x, h1.y, h1.z, h1.w};
        float w_r[8]  = {w0.x, w0.y, w0.z, w0.w, w1.x, w1.y, w1.z, w1.w};
        float w2_r[8];
#pragma unroll
        for (int j = 0; j < 8; ++j) w2_r[j] = -2.f * w_r[j];
        int s0g = half * 256 + wave * 16;
        for (int i = 0; i < 16; i += 4) {
            bf16x8 pv[4];
#pragma unroll
            for (int q = 0; q < 4; ++q)
                pv[q] = *(const bf16x8*)(proj + ((size_t)(b * 512 + s0g + i + q) << 9) + lane * 8);
#pragma unroll
            for (int q = 0; q < 4; ++q) {
                float a = 0.f;
#pragma unroll
                for (int j = 0; j < 8; ++j) {
                    float xv = bf2f((unsigned short)pv[q][j]) + hp_r[j];
                    float r = __builtin_amdgcn_rcpf(__builtin_amdgcn_exp2f(2.885390082f * xv) + 1.f);
                    a += w_r[j];
                    a = fmaf(w2_r[j], r, a);
                }
#pragma unroll
                for (int off = 32; off > 0; off >>= 1) a += __shfl_xor(a, off, 64);
                if (lane == 0) sh_e[wave * 16 + i + q] = a;
            }
        }
    }
    __syncthreads();

    // ---- partial softmax over 256 (waves 0..3) ----
    if (tid < 256) {
        float v = sh_e[tid];
        float m = v;
#pragma unroll
        for (int off = 32; off > 0; off >>= 1) m = fmaxf(m, __shfl_xor(m, off, 64));
        if (lane == 0) sh_red[wave] = m;
    }
    __syncthreads();
    if (tid < 256) {
        float mh = fmaxf(fmaxf(sh_red[0], sh_red[1]), fmaxf(sh_red[2], sh_red[3]));
        float p = __builtin_amdgcn_exp2f(1.442695041f * (sh_e[tid] - mh));
        float ss = p;
#pragma unroll
        for (int off = 32; off > 0; off >>= 1) ss += __shfl_xor(ss, off, 64);
        if (lane == 0) sh_red[4 + wave] = ss;
        sh_alpha[tid] = p;
    }
    __syncthreads();
    if (tid == 0) {
        pm[half * 128 + b] = fmaxf(fmaxf(sh_red[0], sh_red[1]), fmaxf(sh_red[2], sh_red[3]));
        ps[half * 128 + b] = sh_red[4] + sh_red[5] + sh_red[6] + sh_red[7];
    }

    // ---- partial context: c_i[col] = sum_{s in half} p[s]*x[b,s,col] ----
    {
        int cc = wave >> 3, sg = wave & 7;
        int col = cc * 256 + lane * 4;
        float a0 = 0.f, a1 = 0.f, a2 = 0.f, a3 = 0.f;
#pragma unroll 4
        for (int sl = sg; sl < 256; sl += 8) {
            float al = sh_alpha[sl];
            int s = half * 256 + sl;
            ushort4 xv = *(const ushort4*)(xb + ((size_t)(b * 512 + s) << 9) + col);
            a0 = fmaf(al, bf2f(xv.x), a0);
            a1 = fmaf(al, bf2f(xv.y), a1);
            a2 = fmaf(al, bf2f(xv.z), a2);
            a3 = fmaf(al, bf2f(xv.w), a3);
        }
        *(float4*)&shp[sg][col] = make_float4(a0, a1, a2, a3);
    }
    __syncthreads();
    if (tid < 512) {
        float s = 0.f;
#pragma unroll
        for (int r = 0; r < 8; ++r) s += shp[r][tid];
        pc[(size_t)(half * 128 + b) * 512 + tid] = s;
    }
}

// ---------------- probs = hs @ W_gen + b_gen; 400 blocks x 64 thr, 8 rows/block ----------------
__global__ __launch_bounds__(64) void gen_probs(const float* __restrict__ hs,
                                                const float* __restrict__ Wg,
                                                const float* __restrict__ bg,
                                                float* __restrict__ out) {
    __shared__ float sh[8][512];
    int r0 = blockIdx.x * 8;
    int tid = threadIdx.x;
#pragma unroll
    for (int q = 0; q < 8; ++q) {
        int row = r0 + q;
        int b = row / T_, t = row % T_;
        const float* hrow = hs + ((size_t)t * B_ + b) * H_;
        for (int i = tid; i < 512; i += 64) sh[q][i] = hrow[i];
    }
    __syncthreads();
    float acc[8];
#pragma unroll
    for (int q = 0; q < 8; ++q) acc[q] = bg[tid];
#pragma unroll 4
    for (int k = 0; k < 512; ++k) {
        float w = Wg[k * 64 + tid];
#pragma unroll
        for (int q = 0; q < 8; ++q) acc[q] = fmaf(sh[q][k], w, acc[q]);
    }
#pragma unroll
    for (int q = 0; q < 8; ++q) out[(size_t)(r0 + q) * 64 + tid] = acc[q];
}

extern "C" void kernel_launch(void* const* d_in, const int* in_sizes, int n_in,
                              void* d_out, int out_size, void* d_ws, size_t ws_size,
                              hipStream_t stream) {
    const float* x       = (const float*)d_in[0];
    const int*   text    = (const int*)d_in[1];
    const float* W_i2h   = (const float*)d_in[2];
    const float* W_h2h   = (const float*)d_in[3];
    const float* b_h2h   = (const float*)d_in[4];
    const float* W_score = (const float*)d_in[5];
    const float* W_lstm  = (const float*)d_in[6];
    const float* U_lstm  = (const float*)d_in[7];
    const float* b_lstm  = (const float*)d_in[8];
    const float* W_gen   = (const float*)d_in[9];
    const float* b_gen   = (const float*)d_in[10];
    float* out = (float*)d_out;

    char* ws = (char*)d_ws;
    unsigned short* x_bf    = (unsigned short*)ws;                 // 67,108,864
    unsigned short* proj_bf = (unsigned short*)(ws + 67108864);    // 67,108,864
    unsigned short* Wt_bf   = (unsigned short*)(ws + 134217728);   //    524,288
    unsigned short* Wh_bf   = (unsigned short*)(ws + 134742016);   //    524,288
    unsigned short* WU_t    = (unsigned short*)(ws + 135266304);   //  4,194,304
    float* c2      = (float*)(ws + 139460608);                     //    524,288 (2 copies)
    unsigned short* inp_bf = (unsigned short*)(ws + 139984896);    //    262,144
    float* z_buf   = (float*)(ws + 140247040);                     //  1,048,576
    float* pc      = (float*)(ws + 141295616);                     //    524,288
    float* pm      = (float*)(ws + 141819904);                     //      1,024
    float* ps      = (float*)(ws + 141820928);                     //      1,024
    float* hs      = (float*)(ws + 141821952);                     // 13,107,200

    setup_k<<<dim3(3200), 512, 0, stream>>>(W_i2h, W_h2h, W_lstm, U_lstm,
                                            Wt_bf, Wh_bf, WU_t, c2, inp_bf);
    conv_x<<<dim3(32768), 256, 0, stream>>>(x, x_bf);
    gemm_proj<<<dim3(4, 512), 256, 0, stream>>>(x_bf, Wt_bf, proj_bf);
    // partial ectx for t=0 with hp = b_h2h
    ghp_e2<<<dim3(256), 1024, 0, stream>>>(z_buf, text, W_lstm, b_lstm, Wh_bf, b_h2h,
                                           c2, hs, inp_bf, proj_bf, x_bf, W_score,
                                           pc, pm, ps, -1);
    for (int t = 0; t < T_; ++t) {
        z_gemm<<<dim3(32), 512, 0, stream>>>(inp_bf, WU_t, pc, pm, ps, z_buf);
        ghp_e2<<<dim3(256), 1024, 0, stream>>>(z_buf, text, W_lstm, b_lstm, Wh_bf, b_h2h,
                                               c2, hs + (size_t)t * (B_ * H_),
                                               inp_bf, proj_bf, x_bf, W_score,
                                               pc, pm, ps, t);
    }
    gen_probs<<<dim3(400), 64, 0, stream>>>(hs, W_gen, b_gen, out);
}

// Round 16
// 1342.850 us; speedup vs baseline: 1.0990x; 1.0418x over previous
//
#include <hip/hip_runtime.h>
#include <hip/hip_bf16.h>

#define B_ 128
#define S_ 512
#define C_ 512
#define H_ 512
#define NC_ 64
#define T_ 25
#define TEXTW (T_ + 1)

typedef __attribute__((ext_vector_type(8))) short bf16x8;
typedef __attribute__((ext_vector_type(8))) unsigned short u16x8;
typedef __attribute__((ext_vector_type(4))) float f32x4;

__device__ __forceinline__ float bf2f(unsigned short u) {
    union { unsigned int i; float f; } v; v.i = ((unsigned int)u) << 16; return v.f;
}
__device__ __forceinline__ unsigned short f2bf(float f) {
    union { float f; unsigned int u; } v; v.f = f;
    unsigned int r = (v.u + 0x7FFFu + ((v.u >> 16) & 1u)) >> 16;
    return (unsigned short)r;
}
__device__ __forceinline__ void gload_lds16(const void* g, void* l) {
    __builtin_amdgcn_global_load_lds(
        (const __attribute__((address_space(1))) unsigned int*)g,
        (__attribute__((address_space(3))) unsigned int*)l, 16, 0, 0);
}
__device__ __forceinline__ float fast_tanh(float x) {
    float e = __builtin_amdgcn_exp2f(2.885390082f * x);
    return 1.f - 2.f * __builtin_amdgcn_rcpf(e + 1.f);
}
__device__ __forceinline__ float fast_sigmoid(float x) {
    return __builtin_amdgcn_rcpf(1.f + __builtin_amdgcn_exp2f(-1.442695041f * x));
}

// ---------------- setup: init state + all weight conversions ----------------
__global__ __launch_bounds__(512) void setup_k(
    const float* __restrict__ Wi, const float* __restrict__ Wh,
    const float* __restrict__ Wl, const float* __restrict__ Ul,
    unsigned short* __restrict__ Wt_bf, unsigned short* __restrict__ Wh_bf,
    unsigned short* __restrict__ WU_t,
    float* __restrict__ c2, unsigned short* __restrict__ inp) {
    int blk = blockIdx.x, tid = threadIdx.x;
    if (blk < 128) {
        c2[blk * 512 + tid] = 0.f;
        c2[65536 + blk * 512 + tid] = 0.f;
        inp[blk * 1024 + 512 + tid] = 0;
    } else if (blk < 640) {
        int n = blk - 128;
        Wt_bf[n * 512 + tid] = f2bf(Wi[tid * 512 + n]);
    } else if (blk < 1152) {
        int i = (blk - 640) * 512 + tid;
        Wh_bf[i] = f2bf(Wh[i]);
    } else {
        int np = blk - 1152;
        int h = np >> 2, g = np & 3;
        {
            float v = Wl[(size_t)tid * 2048 + g * 512 + h];
            WU_t[(size_t)np * 1024 + tid] = f2bf(v);
        }
        {
            float v = Ul[(size_t)tid * 2048 + g * 512 + h];
            WU_t[(size_t)np * 1024 + 512 + tid] = f2bf(v);
        }
    }
}

// ---------------- x f32 -> bf16 ----------------
__global__ __launch_bounds__(256) void conv_x(const float* __restrict__ in,
                                              unsigned short* __restrict__ out) {
    int i = blockIdx.x * 256 + threadIdx.x;
    const float4 v = ((const float4*)in)[i];
    ushort4 o;
    o.x = f2bf(v.x); o.y = f2bf(v.y); o.z = f2bf(v.z); o.w = f2bf(v.w);
    ((ushort4*)out)[i] = o;
}

// ---------------- proj = x @ W_i2h via MFMA (bf16); 256x128 tile, 512 thr ----------------
__global__ __launch_bounds__(512) void gemm_proj(const unsigned short* __restrict__ A,
                                                 const unsigned short* __restrict__ Bt,
                                                 unsigned short* __restrict__ Cm) {
    __shared__ unsigned short As[256 * 64];   // 32 KB
    __shared__ unsigned short Bs[128 * 64];   // 16 KB
    int tid = threadIdx.x;
    int lane = tid & 63;
    int wid = tid >> 6;
    int wr = wid >> 1, wc = wid & 1;          // 4 (M) x 2 (N) waves, each 64x64
    int row0 = blockIdx.y * 256;
    int col0 = blockIdx.x * 128;

    f32x4 acc[4][4];
#pragma unroll
    for (int i = 0; i < 4; ++i)
#pragma unroll
        for (int j = 0; j < 4; ++j) acc[i][j] = (f32x4){0.f, 0.f, 0.f, 0.f};

    for (int k0 = 0; k0 < 512; k0 += 64) {
#pragma unroll
        for (int i = 0; i < 4; ++i) {
            int e = tid + i * 512;            // 2048 chunks
            int r = e >> 3, cc = e & 7;
            int cs = cc ^ (r & 7);
            gload_lds16(A + (size_t)(row0 + r) * 512 + k0 + cs * 8, &As[e * 8]);
        }
#pragma unroll
        for (int i = 0; i < 2; ++i) {
            int e = tid + i * 512;            // 1024 chunks
            int r = e >> 3, cc = e & 7;
            int cs = cc ^ (r & 7);
            gload_lds16(Bt + (size_t)(col0 + r) * 512 + k0 + cs * 8, &Bs[e * 8]);
        }
        __syncthreads();
#pragma unroll
        for (int ks = 0; ks < 2; ++ks) {
            bf16x8 a[4], b[4];
#pragma unroll
            for (int i = 0; i < 4; ++i) {
                int m = wr * 64 + i * 16 + (lane & 15);
                int ch = (ks * 4 + (lane >> 4)) ^ (m & 7);
                a[i] = *(const bf16x8*)&As[(m * 8 + ch) * 8];
            }
#pragma unroll
            for (int j = 0; j < 4; ++j) {
                int n = wc * 64 + j * 16 + (lane & 15);
                int ch = (ks * 4 + (lane >> 4)) ^ (n & 7);
                b[j] = *(const bf16x8*)&Bs[(n * 8 + ch) * 8];
            }
#pragma unroll
            for (int i = 0; i < 4; ++i)
#pragma unroll
                for (int j = 0; j < 4; ++j)
                    acc[i][j] = __builtin_amdgcn_mfma_f32_16x16x32_bf16(a[i], b[j], acc[i][j], 0, 0, 0);
        }
        __syncthreads();
    }
#pragma unroll
    for (int i = 0; i < 4; ++i)
#pragma unroll
        for (int j = 0; j < 4; ++j) {
            int gcol = col0 + wc * 64 + j * 16 + (lane & 15);
#pragma unroll
            for (int r = 0; r < 4; ++r) {
                int grow = row0 + wr * 64 + i * 16 + (lane >> 4) * 4 + r;
                Cm[(size_t)grow * 512 + gcol] = f2bf(acc[i][j][r]);
            }
        }
}

// ---------------- z = [ctx|h] @ WU_t^T; 64 blocks x 512 thr; BK=128, N-tile 32 ----------------
__global__ __launch_bounds__(512) void z_gemm(
    const unsigned short* __restrict__ inp, const unsigned short* __restrict__ Bt,
    const float* __restrict__ pc, const float* __restrict__ pm,
    const float* __restrict__ ps, float* __restrict__ Z) {
    __shared__ unsigned short As[128 * 128];   // 32 KB
    __shared__ unsigned short Bs[32 * 128];    // 8 KB
    int tid = threadIdx.x;
    int lane = tid & 63;
    int wave = tid >> 6;
    int wr = wave >> 1, wc = wave & 1;    // 4 (M, 32 rows each) x 2 (N, 16 cols each)
    int col0 = blockIdx.x * 32;

    float cw0[4], cw1[4];
    int rr[4], csv[4];
#pragma unroll
    for (int i = 0; i < 4; ++i) {
        int e = tid + i * 512;
        int r = e >> 4, cc = e & 15;
        rr[i] = r; csv[i] = cc ^ (r & 15);
        float m0 = pm[r], m1 = pm[128 + r];
        float s0 = ps[r], s1 = ps[128 + r];
        float M = fmaxf(m0, m1);
        float w0 = __builtin_amdgcn_exp2f(1.442695041f * (m0 - M));
        float w1 = __builtin_amdgcn_exp2f(1.442695041f * (m1 - M));
        float inv = 1.f / (w0 * s0 + w1 * s1);
        cw0[i] = w0 * inv; cw1[i] = w1 * inv;
    }

    f32x4 acc[2];
#pragma unroll
    for (int i = 0; i < 2; ++i) acc[i] = (f32x4){0.f, 0.f, 0.f, 0.f};

    for (int k0 = 0; k0 < 1024; k0 += 128) {
        if (k0 < 512) {
#pragma unroll
            for (int i = 0; i < 4; ++i) {
                int e = tid + i * 512;
                int kb = k0 + csv[i] * 8;
                const float* c0p = pc + rr[i] * 512 + kb;
                const float* c1p = pc + 65536 + rr[i] * 512 + kb;
                float4 c0a = *(const float4*)c0p;
                float4 c0b = *(const float4*)(c0p + 4);
                float4 c1a = *(const float4*)c1p;
                float4 c1b = *(const float4*)(c1p + 4);
                u16x8 o;
                o[0] = f2bf(cw0[i] * c0a.x + cw1[i] * c1a.x);
                o[1] = f2bf(cw0[i] * c0a.y + cw1[i] * c1a.y);
                o[2] = f2bf(cw0[i] * c0a.z + cw1[i] * c1a.z);
                o[3] = f2bf(cw0[i] * c0a.w + cw1[i] * c1a.w);
                o[4] = f2bf(cw0[i] * c0b.x + cw1[i] * c1b.x);
                o[5] = f2bf(cw0[i] * c0b.y + cw1[i] * c1b.y);
                o[6] = f2bf(cw0[i] * c0b.z + cw1[i] * c1b.z);
                o[7] = f2bf(cw0[i] * c0b.w + cw1[i] * c1b.w);
                *(u16x8*)&As[e * 8] = o;
            }
        } else {
#pragma unroll
            for (int i = 0; i < 4; ++i) {
                int e = tid + i * 512;
                gload_lds16(inp + (size_t)rr[i] * 1024 + k0 + csv[i] * 8, &As[e * 8]);
            }
        }
        {
            int e = tid;                      // 512 chunks (32 rows x 16)
            int r = e >> 4, cc = e & 15;
            int cs = cc ^ (r & 15);
            gload_lds16(Bt + (size_t)(col0 + r) * 1024 + k0 + cs * 8, &Bs[e * 8]);
        }
        __syncthreads();
#pragma unroll
        for (int ks = 0; ks < 4; ++ks) {
            bf16x8 a[2], bfr;
#pragma unroll
            for (int i = 0; i < 2; ++i) {
                int m = wr * 32 + i * 16 + (lane & 15);
                int ch = (ks * 4 + (lane >> 4)) ^ (m & 15);
                a[i] = *(const bf16x8*)&As[(m * 16 + ch) * 8];
            }
            {
                int n = wc * 16 + (lane & 15);
                int ch = (ks * 4 + (lane >> 4)) ^ (n & 15);
                bfr = *(const bf16x8*)&Bs[(n * 16 + ch) * 8];
            }
#pragma unroll
            for (int i = 0; i < 2; ++i)
                acc[i] = __builtin_amdgcn_mfma_f32_16x16x32_bf16(a[i], bfr, acc[i], 0, 0, 0);
        }
        __syncthreads();
    }
#pragma unroll
    for (int i = 0; i < 2; ++i) {
        int gcol = col0 + wc * 16 + (lane & 15);
#pragma unroll
        for (int r = 0; r < 4; ++r) {
            int grow = wr * 32 + i * 16 + (lane >> 4) * 4 + r;
            Z[(size_t)grow * 2048 + gcol] = acc[i][r];
        }
    }
}

// ---------------- fused: gates(t)+hp(t) [dup per half] + E/partial-softmax/partial-ctx(t+1) ----------------
// 256 blocks = (half, b); 1024 threads. t==-1: ectx only. t==24: gates only.
__global__ __launch_bounds__(1024) void ghp_e2(
    const float* __restrict__ z, const int* __restrict__ text,
    const float* __restrict__ Wl, const float* __restrict__ bl,
    const unsigned short* __restrict__ Whb, const float* __restrict__ bh2h,
    float* __restrict__ c2, float* __restrict__ hs_t,
    unsigned short* __restrict__ inp,
    const unsigned short* __restrict__ proj, const unsigned short* __restrict__ xb,
    const float* __restrict__ Wscore,
    float* __restrict__ pc, float* __restrict__ pm, float* __restrict__ ps, int t) {
    __shared__ float shg[512];
    __shared__ float gp[16][512];
    __shared__ float sh_hp[512];
    __shared__ float sh_e[256];
    __shared__ float sh_alpha[256];
    __shared__ float sh_red[8];
    __shared__ float shp[8][512];
    int blk = blockIdx.x;
    int half = blk >> 7, b = blk & 127;
    int tid = threadIdx.x, wave = tid >> 6, lane = tid & 63;

    if (t >= 0) {
        // ---- gates (duplicated per half; each half owns its c copy) ----
        if (tid < 512) {
            int ch = text[b * TEXTW + t];
            const float* wrow = Wl + (size_t)(512 + ch) * 2048;
            float4 zv = *(const float4*)(z + (size_t)b * 2048 + tid * 4);
            float zi = zv.x + bl[tid] + wrow[tid];
            float zf = zv.y + bl[512 + tid] + wrow[512 + tid];
            float zg = zv.z + bl[1024 + tid] + wrow[1024 + tid];
            float zo = zv.w + bl[1536 + tid] + wrow[1536 + tid];
            float ig = fast_sigmoid(zi);
            float fg = fast_sigmoid(zf);
            float gg = fast_tanh(zg);
            float og = fast_sigmoid(zo);
            int idx = half * 65536 + b * 512 + tid;
            float cn = fg * c2[idx] + ig * gg;
            c2[idx] = cn;
            float hn = og * fast_tanh(cn);
            if (half == 0) {
                hs_t[b * 512 + tid] = hn;
                inp[b * 1024 + 512 + tid] = f2bf(hn);
            }
            shg[tid] = hn;
        }
        __syncthreads();
        if (t >= T_ - 1) return;
        // ---- hp (full GEMV, duplicated per half); wave owns 32 k, lane owns 8 cols ----
        {
            float r8[8] = {0.f, 0.f, 0.f, 0.f, 0.f, 0.f, 0.f, 0.f};
#pragma unroll 4
            for (int kk = 0; kk < 32; ++kk) {
                int k = wave * 32 + kk;
                float hv = shg[k];
                u16x8 wv = *(const u16x8*)(Whb + k * 512 + lane * 8);
#pragma unroll
                for (int jj = 0; jj < 8; ++jj) r8[jj] = fmaf(hv, bf2f(wv[jj]), r8[jj]);
            }
#pragma unroll
            for (int jj = 0; jj < 8; ++jj) gp[wave][lane * 8 + jj] = r8[jj];
        }
        __syncthreads();
        if (tid < 512) {
            float s = bh2h[tid];
#pragma unroll
            for (int w = 0; w < 16; ++w) s += gp[w][tid];
            sh_hp[tid] = s;
        }
        __syncthreads();
    } else {
        if (tid < 512) sh_hp[tid] = bh2h[tid];
        __syncthreads();
    }

    // ---- E over this half's 256 s-rows; wave owns 16, 4-row prefetch ----
    {
        float4 h0 = *(const float4*)(sh_hp + lane * 8);
        float4 h1 = *(const float4*)(sh_hp + lane * 8 + 4);
        float4 w0 = *(const float4*)(Wscore + lane * 8);
        float4 w1 = *(const float4*)(Wscore + lane * 8 + 4);
        float hp_r[8] = {h0.x, h0.y, h0.z, h0.w, h1.x, h1.y, h1.z, h1.w};
        float w_r[8]  = {w0.x, w0.y, w0.z, w0.w, w1.x, w1.y, w1.z, w1.w};
        float w2_r[8];
#pragma unroll
        for (int j = 0; j < 8; ++j) w2_r[j] = -2.f * w_r[j];
        int s0g = half * 256 + wave * 16;
        for (int i = 0; i < 16; i += 4) {
            bf16x8 pv[4];
#pragma unroll
            for (int q = 0; q < 4; ++q)
                pv[q] = *(const bf16x8*)(proj + ((size_t)(b * 512 + s0g + i + q) << 9) + lane * 8);
#pragma unroll
            for (int q = 0; q < 4; ++q) {
                float a = 0.f;
#pragma unroll
                for (int j = 0; j < 8; ++j) {
                    float xv = bf2f((unsigned short)pv[q][j]) + hp_r[j];
                    float r = __builtin_amdgcn_rcpf(__builtin_amdgcn_exp2f(2.885390082f * xv) + 1.f);
                    a += w_r[j];
                    a = fmaf(w2_r[j], r, a);
                }
#pragma unroll
                for (int off = 32; off > 0; off >>= 1) a += __shfl_xor(a, off, 64);
                if (lane == 0) sh_e[wave * 16 + i + q] = a;
            }
        }
    }
    __syncthreads();

    // ---- partial softmax over 256 (waves 0..3) ----
    if (tid < 256) {
        float v = sh_e[tid];
        float m = v;
#pragma unroll
        for (int off = 32; off > 0; off >>= 1) m = fmaxf(m, __shfl_xor(m, off, 64));
        if (lane == 0) sh_red[wave] = m;
    }
    __syncthreads();
    if (tid < 256) {
        float mh = fmaxf(fmaxf(sh_red[0], sh_red[1]), fmaxf(sh_red[2], sh_red[3]));
        float p = __builtin_amdgcn_exp2f(1.442695041f * (sh_e[tid] - mh));
        float ss = p;
#pragma unroll
        for (int off = 32; off > 0; off >>= 1) ss += __shfl_xor(ss, off, 64);
        if (lane == 0) sh_red[4 + wave] = ss;
        sh_alpha[tid] = p;
    }
    __syncthreads();
    if (tid == 0) {
        pm[half * 128 + b] = fmaxf(fmaxf(sh_red[0], sh_red[1]), fmaxf(sh_red[2], sh_red[3]));
        ps[half * 128 + b] = sh_red[4] + sh_red[5] + sh_red[6] + sh_red[7];
    }

    // ---- partial context: c_i[col] = sum_{s in half} p[s]*x[b,s,col] ----
    {
        int cc = wave >> 3, sg = wave & 7;
        int col = cc * 256 + lane * 4;
        float a0 = 0.f, a1 = 0.f, a2 = 0.f, a3 = 0.f;
#pragma unroll 4
        for (int sl = sg; sl < 256; sl += 8) {
            float al = sh_alpha[sl];
            int s = half * 256 + sl;
            ushort4 xv = *(const ushort4*)(xb + ((size_t)(b * 512 + s) << 9) + col);
            a0 = fmaf(al, bf2f(xv.x), a0);
            a1 = fmaf(al, bf2f(xv.y), a1);
            a2 = fmaf(al, bf2f(xv.z), a2);
            a3 = fmaf(al, bf2f(xv.w), a3);
        }
        *(float4*)&shp[sg][col] = make_float4(a0, a1, a2, a3);
    }
    __syncthreads();
    if (tid < 512) {
        float s = 0.f;
#pragma unroll
        for (int r = 0; r < 8; ++r) s += shp[r][tid];
        pc[(size_t)(half * 128 + b) * 512 + tid] = s;
    }
}

// ---------------- probs = hs @ W_gen + b_gen; 400 blocks x 64 thr, 8 rows/block ----------------
__global__ __launch_bounds__(64) void gen_probs(const float* __restrict__ hs,
                                                const float* __restrict__ Wg,
                                                const float* __restrict__ bg,
                                                float* __restrict__ out) {
    __shared__ float sh[8][512];
    int r0 = blockIdx.x * 8;
    int tid = threadIdx.x;
#pragma unroll
    for (int q = 0; q < 8; ++q) {
        int row = r0 + q;
        int b = row / T_, t = row % T_;
        const float* hrow = hs + ((size_t)t * B_ + b) * H_;
        for (int i = tid; i < 512; i += 64) sh[q][i] = hrow[i];
    }
    __syncthreads();
    float acc[8];
#pragma unroll
    for (int q = 0; q < 8; ++q) acc[q] = bg[tid];
#pragma unroll 4
    for (int k = 0; k < 512; ++k) {
        float w = Wg[k * 64 + tid];
#pragma unroll
        for (int q = 0; q < 8; ++q) acc[q] = fmaf(sh[q][k], w, acc[q]);
    }
#pragma unroll
    for (int q = 0; q < 8; ++q) out[(size_t)(r0 + q) * 64 + tid] = acc[q];
}

extern "C" void kernel_launch(void* const* d_in, const int* in_sizes, int n_in,
                              void* d_out, int out_size, void* d_ws, size_t ws_size,
                              hipStream_t stream) {
    const float* x       = (const float*)d_in[0];
    const int*   text    = (const int*)d_in[1];
    const float* W_i2h   = (const float*)d_in[2];
    const float* W_h2h   = (const float*)d_in[3];
    const float* b_h2h   = (const float*)d_in[4];
    const float* W_score = (const float*)d_in[5];
    const float* W_lstm  = (const float*)d_in[6];
    const float* U_lstm  = (const float*)d_in[7];
    const float* b_lstm  = (const float*)d_in[8];
    const float* W_gen   = (const float*)d_in[9];
    const float* b_gen   = (const float*)d_in[10];
    float* out = (float*)d_out;

    char* ws = (char*)d_ws;
    unsigned short* x_bf    = (unsigned short*)ws;                 // 67,108,864
    unsigned short* proj_bf = (unsigned short*)(ws + 67108864);    // 67,108,864
    unsigned short* Wt_bf   = (unsigned short*)(ws + 134217728);   //    524,288
    unsigned short* Wh_bf   = (unsigned short*)(ws + 134742016);   //    524,288
    unsigned short* WU_t    = (unsigned short*)(ws + 135266304);   //  4,194,304
    float* c2      = (float*)(ws + 139460608);                     //    524,288 (2 copies)
    unsigned short* inp_bf = (unsigned short*)(ws + 139984896);    //    262,144
    float* z_buf   = (float*)(ws + 140247040);                     //  1,048,576
    float* pc      = (float*)(ws + 141295616);                     //    524,288
    float* pm      = (float*)(ws + 141819904);                     //      1,024
    float* ps      = (float*)(ws + 141820928);                     //      1,024
    float* hs      = (float*)(ws + 141821952);                     // 13,107,200

    setup_k<<<dim3(3200), 512, 0, stream>>>(W_i2h, W_h2h, W_lstm, U_lstm,
                                            Wt_bf, Wh_bf, WU_t, c2, inp_bf);
    conv_x<<<dim3(32768), 256, 0, stream>>>(x, x_bf);
    gemm_proj<<<dim3(4, 256), 512, 0, stream>>>(x_bf, Wt_bf, proj_bf);
    // partial ectx for t=0 with hp = b_h2h
    ghp_e2<<<dim3(256), 1024, 0, stream>>>(z_buf, text, W_lstm, b_lstm, Wh_bf, b_h2h,
                                           c2, hs, inp_bf, proj_bf, x_bf, W_score,
                                           pc, pm, ps, -1);
    for (int t = 0; t < T_; ++t) {
        z_gemm<<<dim3(64), 512, 0, stream>>>(inp_bf, WU_t, pc, pm, ps, z_buf);
        ghp_e2<<<dim3(256), 1024, 0, stream>>>(z_buf, text, W_lstm, b_lstm, Wh_bf, b_h2h,
                                               c2, hs + (size_t)t * (B_ * H_),
                                               inp_bf, proj_bf, x_bf, W_score,
                                               pc, pm, ps, t);
    }
    gen_probs<<<dim3(400), 64, 0, stream>>>(hs, W_gen, b_gen, out);
}